// Round 9
// baseline (260.687 us; speedup 1.0000x reference)
//
#include <hip/hip_runtime.h>
#include <hip/hip_fp16.h>
#include <math.h>

#define N_NODES 50000
#define N_EDGES 800000
#define CAP 64                     // fixed per-node csr/meta capacity (deg>CAP -> ovf list)
#define OVF_CAP 65536
// dims: IN=128, HIDDEN=128, NUM_CLASSES=64 (hard-coded)
// Algebra: GraphConv chain is linear ->
//   logits = A^3 (h1 @ Wp) + t*c1 + d*c2 + bc
//   Wp = W1@W2@Wc, c1 = b1@W2@Wc, c2 = b2@Wc, d[v] = [deg_v>0] (=sum alpha), t = A d.
// Round-9 = round-8 + ONE delta-cluster (k1 internal): build blocks FIRST in the
//   dispatch order + 4 edges/thread (4 independent load->atomic->store chains in
//   flight per thread). Round-8 counters: k1 occ 24% despite LDS halved -> limiter
//   is TLP/ILP of the build, not LDS. GEMM blocks now trail, absorbed in build tail.
// Round-8 lesson: LDS wasn't k1's occupancy cap; per-thread MLP=1 was suspect.
// Round-7 lesson: single-pass fixed-cap CSR works.
// Round-6 lesson: latency-bound edge passes absorb compute blocks for free.
// Round-3 lesson: keep simple dual-chain gather loops; pads gather node0 (L1-hot).

typedef _Float16 half8 __attribute__((ext_vector_type(8)));
typedef float floatx16 __attribute__((ext_vector_type(16)));

#define NPREPA_BLK 129   // 129*256 = 33024 >= 32896
#define NZERO_BLK 587    // 587*256 = 150272 >= 150001 (deg + el2 + ovfn)
#define NPREPP_BLK 33    // 33*256 = 8448 >= 8320
#define NGEMM_BLK 391    // ceil(50000/128)
#define NEDGE4_BLK 782   // 782*256*4 = 800768 >= 800000 (4 edges/thread)

// ---------------- K0: prep_a (blocks 0..128) + zero-fill (blocks 129..) ----------------
__global__ __launch_bounds__(256) void k0_prep_zero(const float* __restrict__ Wg,
                                                    const float* __restrict__ W1,
                                                    const float* __restrict__ W2,
                                                    const float* __restrict__ b1,
                                                    __half* __restrict__ Wg_hl,
                                                    float* __restrict__ W12,
                                                    float* __restrict__ c12,
                                                    int* __restrict__ deg,
                                                    float* __restrict__ el2f,
                                                    int* __restrict__ ovfn) {
  int b = blockIdx.x;
  if (b >= NPREPA_BLK) {                 // ---- zero: deg, el2, ovfn ----
    int i = (b - NPREPA_BLK) * 256 + threadIdx.x;
    if (i < N_NODES) deg[i] = 0;
    else if (i < 3 * N_NODES) el2f[i - N_NODES] = 0.f;
    else if (i == 3 * N_NODES) *ovfn = 0;
    return;
  }
  // ---- prep_a: Wg -> hi/lo frags; W12 = W1@W2; c12 = b1@W2 ----
  int e = b * 256 + threadIdx.x;
  if (e < 16384) {
    _Float16* o = (_Float16*)Wg_hl;
    int k = e >> 7, n = e & 127;
    float w = Wg[k * 128 + n];
    _Float16 hi = (_Float16)w;
    float lo = w - (float)hi;
    int oi = (((k >> 3) * 128 + n) << 3) | (k & 7);
    o[oi] = hi;
    o[16384 + oi] = (_Float16)lo;
  } else if (e < 32768) {
    int local = e - 16384;
    int k = local >> 7, n = local & 127;
    float acc = 0.f;
    for (int j = 0; j < 128; ++j) acc = fmaf(W1[k * 128 + j], W2[j * 128 + n], acc);
    W12[k * 128 + n] = acc;
  } else if (e < 32896) {
    int n = e - 32768;
    float acc = 0.f;
    for (int j = 0; j < 128; ++j) acc = fmaf(b1[j], W2[j * 128 + n], acc);
    c12[n] = acc;
  }
}

// ---------------- MFMA GEMM body: C16[M x NCOL] = fp16( A[M x 128] @ (Whi+Wlo) ) ----------------
// Two-phase A-staging: 8 k-chunks at a time through a 16.6 KB LDS buffer; all 8
// frags end in VGPRs before the MFMA loop. ELR epilogue writes el2.x and er.
template <int NCOL, bool A16, bool ELR>
__device__ __forceinline__ void mgemm_body(int bid, const void* __restrict__ Ap,
                                           const __half* __restrict__ Whl,
                                           __half* __restrict__ C16, int M,
                                           const float* __restrict__ al,
                                           const float* __restrict__ ar,
                                           float* __restrict__ el2x,
                                           float* __restrict__ er) {
  __shared__ __half Al[8][129][8];       // 16.5 KB
  const int tid  = threadIdx.x;
  const int row0 = bid * 128;
  const int lane = tid & 63;
  const int lane31 = lane & 31;
  const int q = lane >> 5;
  const int r = tid >> 6;

  half8 afr[8];
  #pragma unroll
  for (int h = 0; h < 2; ++h) {
    if (h) __syncthreads();              // prior frag reads done before overwrite
    if (A16) {
      const uint4* A8 = (const uint4*)Ap;
      #pragma unroll
      for (int i = 0; i < 4; ++i) {
        int idx = tid + i * 256;
        int row = idx >> 3, c = idx & 7;   // 128 rows x 8 chunks
        int grow = row0 + row;
        uint4 v = make_uint4(0u, 0u, 0u, 0u);
        if (grow < M) v = A8[grow * 16 + h * 8 + c];
        *reinterpret_cast<uint4*>(&Al[c][row][0]) = v;
      }
    } else {
      const float4* A4 = (const float4*)Ap;
      #pragma unroll
      for (int i = 0; i < 4; ++i) {
        int idx = tid + i * 256;
        int row = idx >> 3, c = idx & 7;
        int grow = row0 + row;
        half8 hv = {};
        if (grow < M) {
          float4 a0 = A4[grow * 32 + (h * 8 + c) * 2];
          float4 a1 = A4[grow * 32 + (h * 8 + c) * 2 + 1];
          hv[0] = (_Float16)a0.x; hv[1] = (_Float16)a0.y;
          hv[2] = (_Float16)a0.z; hv[3] = (_Float16)a0.w;
          hv[4] = (_Float16)a1.x; hv[5] = (_Float16)a1.y;
          hv[6] = (_Float16)a1.z; hv[7] = (_Float16)a1.w;
        }
        *reinterpret_cast<half8*>(&Al[c][row][0]) = hv;
      }
    }
    __syncthreads();
    #pragma unroll
    for (int s2 = 0; s2 < 4; ++s2) {     // global chunk 2s+q, local chunk 2*s2+q
      afr[h * 4 + s2] =
          *reinterpret_cast<const half8*>(&Al[2 * s2 + q][r * 32 + lane31][0]);
    }
  }

  const half8* B8 = reinterpret_cast<const half8*>(Whl);
  const int KN8 = 16 * NCOL;

  float elp[16], erp[16];
  if (ELR) {
    #pragma unroll
    for (int i = 0; i < 16; ++i) { elp[i] = 0.f; erp[i] = 0.f; }
  }

  #pragma unroll
  for (int tc = 0; tc < NCOL / 32; ++tc) {
    floatx16 acc = {};
    int nbase = tc * 32 + lane31;
    #pragma unroll
    for (int s = 0; s < 8; ++s) {
      int ci = (2 * s + q) * NCOL + nbase;
      half8 bl = B8[KN8 + ci];
      half8 bh = B8[ci];
      acc = __builtin_amdgcn_mfma_f32_32x32x16_f16(afr[s], bl, acc, 0, 0, 0);
      acc = __builtin_amdgcn_mfma_f32_32x32x16_f16(afr[s], bh, acc, 0, 0, 0);
    }
    if (ELR) {
      float alv = al[nbase], arv = ar[nbase];
      #pragma unroll
      for (int i = 0; i < 16; ++i) {
        elp[i] = fmaf(acc[i], alv, elp[i]);
        erp[i] = fmaf(acc[i], arv, erp[i]);
      }
    }
    #pragma unroll
    for (int i = 0; i < 16; ++i) {
      int rl = (i & 3) + 8 * (i >> 2) + 4 * q;
      int grow = row0 + r * 32 + rl;
      if (grow < M) C16[grow * NCOL + nbase] = __float2half(acc[i]);
    }
  }

  if (ELR) {
    #pragma unroll
    for (int off = 1; off <= 16; off <<= 1) {
      #pragma unroll
      for (int i = 0; i < 16; ++i) {
        elp[i] += __shfl_xor(elp[i], off);
        erp[i] += __shfl_xor(erp[i], off);
      }
    }
    if (lane31 == 0) {
      #pragma unroll
      for (int i = 0; i < 16; ++i) {
        int rl = (i & 3) + 8 * (i >> 2) + 4 * q;
        int grow = row0 + r * 32 + rl;
        if (grow < M) {
          er[grow] = erp[i];
          el2x[2 * grow] = elp[i];     // .x only; .y written by CSR-build path
        }
      }
    }
  }
}

// ---------------- K1: csr-build (0..781, 4 edges/thr) + prepP + mgemm128 (trail) ----------------
// Build blocks dispatched FIRST: flood CUs with latency-bound edge chains; GEMM
// blocks trail and are absorbed into the build's idle issue slots / tail.
__global__ __launch_bounds__(256) void k1_fused(const int* __restrict__ src,
                                                const int* __restrict__ dst,
                                                int* __restrict__ deg,
                                                int* __restrict__ csr,
                                                float* __restrict__ el2f,
                                                int2* __restrict__ ovf,
                                                int* __restrict__ ovfn,
                                                const float* __restrict__ W12,
                                                const float* __restrict__ c12,
                                                const float* __restrict__ Wc,
                                                const float* __restrict__ b2,
                                                __half* __restrict__ WPhl,
                                                float* __restrict__ c1,
                                                float* __restrict__ c2,
                                                const float* __restrict__ x,
                                                const __half* __restrict__ Wg_hl,
                                                __half* __restrict__ P16,
                                                const float* __restrict__ al,
                                                const float* __restrict__ ar,
                                                float2* __restrict__ el2,
                                                float* __restrict__ er, int N) {
  int b = blockIdx.x;
  if (b < NEDGE4_BLK) {                  // ---- csr build: 4 edges per thread ----
    int eb = b * 1024 + threadIdx.x;     // edges eb + {0,256,512,768}
    int d[4], s[4], rr[4];
    bool v[4];
    #pragma unroll
    for (int u = 0; u < 4; ++u) {        // 4 independent loads in flight
      int e = eb + u * 256;
      v[u] = (e < N_EDGES);
      d[u] = v[u] ? dst[e] : 0;
      s[u] = v[u] ? src[e] : 0;
    }
    #pragma unroll
    for (int u = 0; u < 4; ++u)          // 4 independent atomics in flight
      rr[u] = v[u] ? atomicAdd(&deg[d[u]], 1) : 0;
    #pragma unroll
    for (int u = 0; u < 4; ++u) {
      if (!v[u]) continue;
      if (rr[u] == 0) el2f[2 * d[u] + 1] = 1.0f;
      if (rr[u] < CAP) {
        csr[d[u] * CAP + rr[u]] = s[u];
      } else {
        int j = atomicAdd(ovfn, 1);
        if (j < OVF_CAP) ovf[j] = make_int2(d[u], s[u]);
      }
    }
    return;
  }
  if (b < NEDGE4_BLK + NPREPP_BLK) {     // ---- prepP ----
    int e = (b - NEDGE4_BLK) * 256 + threadIdx.x;
    _Float16* o = (_Float16*)WPhl;
    if (e < 8192) {
      int k = e >> 6, n = e & 63;
      float acc = 0.f;
      for (int j = 0; j < 128; ++j) acc = fmaf(W12[k * 128 + j], Wc[j * 64 + n], acc);
      _Float16 hi = (_Float16)acc;
      float lo = acc - (float)hi;
      int oi = (((k >> 3) * 64 + n) << 3) | (k & 7);
      o[oi] = hi;
      o[8192 + oi] = (_Float16)lo;
    } else if (e < 8256) {
      int n = e - 8192;
      float acc = 0.f;
      for (int j = 0; j < 128; ++j) acc = fmaf(c12[j], Wc[j * 64 + n], acc);
      c1[n] = acc;
    } else if (e < 8320) {
      int n = e - 8256;
      float acc = 0.f;
      for (int j = 0; j < 128; ++j) acc = fmaf(b2[j], Wc[j * 64 + n], acc);
      c2[n] = acc;
    }
    return;
  }
  // ---- mgemm128 (trailing blocks): h16, el2.x, er ----
  mgemm_body<128, false, true>(b - NEDGE4_BLK - NPREPP_BLK, x, Wg_hl, P16, N, al, ar,
                               reinterpret_cast<float*>(el2), er);
}

// ---------------- standalone mgemm64 wrapper ----------------
__global__ __launch_bounds__(256) void mgemm64_k(const void* __restrict__ Ap,
                                                 const __half* __restrict__ Whl,
                                                 __half* __restrict__ C16, int M) {
  mgemm_body<64, true, false>(blockIdx.x, Ap, Whl, C16, M, nullptr, nullptr, nullptr, nullptr);
}

__device__ inline void fma8(float2 acc[4], uint4 u, float a) {
  __half2* h = reinterpret_cast<__half2*>(&u);
  #pragma unroll
  for (int j = 0; j < 4; ++j) {
    float2 f = __half22float2(h[j]);
    acc[j].x = fmaf(a, f.x, acc[j].x);
    acc[j].y = fmaf(a, f.y, acc[j].y);
  }
}

// ---------------- fused edge-softmax + t + agg 128 (GAT layer), LDS-staged meta ----------------
// Fixed-capacity layout: node w's slots = [w*CAP, w*CAP+pcnt), pcnt=round16(deg) in [16,64].
// Softmax in-register -> meta {src*16, alpha} (pads {0,0}) AND per-wave LDS copy.
// NOTE: out (h1) overlays csr: each node's csr slots are read ONLY by its own wave,
// before that wave writes out[w] over the same 256B region. t[w] = sum alpha*[deg_src>0].
__global__ __launch_bounds__(256) void aggsm_k(const int* __restrict__ deg,
                                               const int* __restrict__ csr,
                                               const float2* __restrict__ el2,
                                               const float* __restrict__ er,
                                               int2* __restrict__ meta,
                                               int2* __restrict__ meta_ovf,
                                               const int2* __restrict__ ovf,
                                               const int* __restrict__ ovfn,
                                               float* __restrict__ t,
                                               const __half* __restrict__ hp,
                                               __half* __restrict__ out, int N) {
  __shared__ int2 lmeta[4][64];
  int wv   = threadIdx.x >> 6;
  int w    = (blockIdx.x * 256 + threadIdx.x) >> 6;
  int lane = threadIdx.x & 63;
  if (w >= N) return;
  int o0  = w * CAP;
  int cnt = deg[w];
  int q  = lane >> 4;
  int fl = lane & 15;
  const uint4* hpq = reinterpret_cast<const uint4*>(hp);

  int pcnt;
  if (cnt <= CAP) {                      // wave-uniform fast path (covers cnt==0)
    pcnt = (cnt + 15) & ~15;
    if (pcnt < 16) pcnt = 16;
    bool valid = lane < cnt;
    float erv = er[w];
    int s = 0;
    float ev = -3.4e38f, flag = 0.f;
    if (valid) {
      s = csr[o0 + lane];
      float2 e2 = el2[s];
      float e0 = e2.x + erv;
      ev = (e0 >= 0.f) ? e0 : 0.2f * e0;
      flag = e2.y;
    }
    float m = ev;
    #pragma unroll
    for (int off = 32; off; off >>= 1) m = fmaxf(m, __shfl_xor(m, off));
    float ee = valid ? __expf(ev - m) : 0.f;
    float sum = ee, tp = ee * flag;
    #pragma unroll
    for (int off = 32; off; off >>= 1) {
      sum += __shfl_xor(sum, off);
      tp  += __shfl_xor(tp, off);
    }
    float inv = (cnt > 0) ? 1.f / sum : 0.f;
    int2 mm = make_int2(0, 0);
    if (valid) mm = make_int2(s * 16, __float_as_int(ee * inv));
    if (lane < pcnt) meta[o0 + lane] = mm;
    lmeta[wv][lane] = mm;
    if (lane == 0) t[w] = tp * inv;
  } else {                               // rare generic path (degree > CAP): 64 fixed + ovf
    pcnt = CAP;
    int ovn = *ovfn;
    if (ovn > OVF_CAP) ovn = OVF_CAP;
    float erv = er[w];
    int s0 = csr[o0 + lane];             // all 64 slots valid
    float2 e20 = el2[s0];
    float ev0 = e20.x + erv;
    ev0 = (ev0 >= 0.f) ? ev0 : 0.2f * ev0;
    float m = ev0;
    for (int j = lane; j < ovn; j += 64) {
      int2 ov = ovf[j];
      if (ov.x == w) {
        float2 e2 = el2[ov.y];
        float ev = e2.x + erv;
        ev = (ev >= 0.f) ? ev : 0.2f * ev;
        m = fmaxf(m, ev);
      }
    }
    #pragma unroll
    for (int off = 32; off; off >>= 1) m = fmaxf(m, __shfl_xor(m, off));
    float ee0 = __expf(ev0 - m);
    float sum = ee0, tacc = ee0 * e20.y;
    for (int j = lane; j < ovn; j += 64) {
      int2 ov = ovf[j];
      if (ov.x == w) {
        float2 e2 = el2[ov.y];
        float ev = e2.x + erv;
        ev = (ev >= 0.f) ? ev : 0.2f * ev;
        float ee = __expf(ev - m);
        meta_ovf[j] = make_int2(ov.y * 16, __float_as_int(ee));
        sum += ee;
        tacc += ee * e2.y;
      }
    }
    #pragma unroll
    for (int off = 32; off; off >>= 1) {
      sum  += __shfl_xor(sum, off);
      tacc += __shfl_xor(tacc, off);
    }
    float inv = 1.f / sum;
    if (lane == 0) t[w] = tacc * inv;
    int2 mm = make_int2(s0 * 16, __float_as_int(ee0 * inv));
    meta[o0 + lane] = mm;
    lmeta[wv][lane] = mm;
    for (int j = lane; j < ovn; j += 64) {
      if (ovf[j].x == w) {
        int2 t2 = meta_ovf[j];
        meta_ovf[j] = make_int2(t2.x, __float_as_int(__int_as_float(t2.y) * inv));
      }
    }
  }

  // mask-free aggregation off LDS meta; ovf tail for deg>CAP nodes only.
  float2 acc0[4] = {}, acc1[4] = {};
  int pc = pcnt;                         // multiple of 16, in [16, 64]
  int2 mA = lmeta[wv][q], mB = lmeta[wv][4 + q];
  for (int base = 8; base < pc; base += 8) {
    int2 nA = lmeta[wv][base + q], nB = lmeta[wv][base + 4 + q];
    uint4 vA = hpq[mA.x + fl], vB = hpq[mB.x + fl];
    fma8(acc0, vA, __int_as_float(mA.y));
    fma8(acc1, vB, __int_as_float(mB.y));
    mA = nA; mB = nB;
  }
  {
    uint4 vA = hpq[mA.x + fl], vB = hpq[mB.x + fl];
    fma8(acc0, vA, __int_as_float(mA.y));
    fma8(acc1, vB, __int_as_float(mB.y));
  }
  if (cnt > CAP) {                       // overflow tail (expected empty)
    int ovn = *ovfn;
    if (ovn > OVF_CAP) ovn = OVF_CAP;
    for (int j = q; j < ovn; j += 4) {
      if (ovf[j].x == w) {
        int2 mm2 = meta_ovf[j];
        fma8(acc0, hpq[mm2.x + fl], __int_as_float(mm2.y));
      }
    }
  }
  #pragma unroll
  for (int j = 0; j < 4; ++j) { acc0[j].x += acc1[j].x; acc0[j].y += acc1[j].y; }
  #pragma unroll
  for (int off = 16; off <= 32; off <<= 1) {
    #pragma unroll
    for (int j = 0; j < 4; ++j) {
      acc0[j].x += __shfl_xor(acc0[j].x, off);
      acc0[j].y += __shfl_xor(acc0[j].y, off);
    }
  }
  if (q == 0) {
    float o8[8];
    #pragma unroll
    for (int j = 0; j < 4; ++j) { o8[2 * j] = acc0[j].x; o8[2 * j + 1] = acc0[j].y; }
    #pragma unroll
    for (int j = 0; j < 8; ++j) o8[j] = (o8[j] > 0.f) ? o8[j] : (__expf(o8[j]) - 1.f);
    __half2 p0 = __floats2half2_rn(o8[0], o8[1]);
    __half2 p1 = __floats2half2_rn(o8[2], o8[3]);
    __half2 p2 = __floats2half2_rn(o8[4], o8[5]);
    __half2 p3 = __floats2half2_rn(o8[6], o8[7]);
    uint4 pk;
    pk.x = *reinterpret_cast<unsigned*>(&p0);
    pk.y = *reinterpret_cast<unsigned*>(&p1);
    pk.z = *reinterpret_cast<unsigned*>(&p2);
    pk.w = *reinterpret_cast<unsigned*>(&p3);
    *reinterpret_cast<uint4*>(&out[w * 128 + fl * 8]) = pk;
  }
}

// ---------------- agg 64-feat via fixed-capacity meta, mask-free, 2-deep dual chain ----------------
// pcnt = round16(deg) in [16,64]; dual chains (slots o+16k / o+8+16k) for MLP.
// deg>CAP nodes add the ovf tail. FINAL adds t*c1 + d*c2 + bc and writes f32; else fp16.
template <bool FINAL>
__global__ __launch_bounds__(256) void agg64v_k(const int* __restrict__ deg,
                                                const int2* __restrict__ meta,
                                                const int2* __restrict__ meta_ovf,
                                                const int2* __restrict__ ovf,
                                                const int* __restrict__ ovfn,
                                                const __half* __restrict__ zp,
                                                const float* __restrict__ t,
                                                const float* __restrict__ c1,
                                                const float* __restrict__ c2,
                                                const float* __restrict__ bc,
                                                void* __restrict__ outp, int N) {
  int w    = (blockIdx.x * 256 + threadIdx.x) >> 6;
  int lane = threadIdx.x & 63;
  if (w >= N) return;
  int dv = deg[w];
  int pc = (dv + 15) & ~15;
  if (pc < 16) pc = 16;
  if (pc > CAP) pc = CAP;
  int o0 = w * CAP, o1 = w * CAP + pc;
  int o   = lane >> 3;
  int fl  = lane & 7;
  const uint4* hpq = reinterpret_cast<const uint4*>(zp);

  float2 acc0[4] = {}, acc1[4] = {};
  int p = o0 + o;
  int2 mA = meta[p], mB = meta[p + 8];
  for (; p + 16 < o1; p += 16) {
    int2 nA = meta[p + 16], nB = meta[p + 24];
    uint4 vA = hpq[(mA.x >> 1) + fl];
    uint4 vB = hpq[(mB.x >> 1) + fl];
    fma8(acc0, vA, __int_as_float(mA.y));
    fma8(acc1, vB, __int_as_float(mB.y));
    mA = nA; mB = nB;
  }
  {
    uint4 vA = hpq[(mA.x >> 1) + fl];
    uint4 vB = hpq[(mB.x >> 1) + fl];
    fma8(acc0, vA, __int_as_float(mA.y));
    fma8(acc1, vB, __int_as_float(mB.y));
  }
  if (dv > CAP) {                        // overflow tail (expected empty)
    int ovn = *ovfn;
    if (ovn > OVF_CAP) ovn = OVF_CAP;
    for (int j = o; j < ovn; j += 8) {
      if (ovf[j].x == w) {
        int2 mm2 = meta_ovf[j];
        fma8(acc0, hpq[(mm2.x >> 1) + fl], __int_as_float(mm2.y));
      }
    }
  }
  #pragma unroll
  for (int j = 0; j < 4; ++j) { acc0[j].x += acc1[j].x; acc0[j].y += acc1[j].y; }
  #pragma unroll
  for (int off = 8; off <= 32; off <<= 1) {
    #pragma unroll
    for (int j = 0; j < 4; ++j) {
      acc0[j].x += __shfl_xor(acc0[j].x, off);
      acc0[j].y += __shfl_xor(acc0[j].y, off);
    }
  }
  if (o == 0) {
    float o8[8];
    #pragma unroll
    for (int j = 0; j < 4; ++j) { o8[2 * j] = acc0[j].x; o8[2 * j + 1] = acc0[j].y; }
    if (FINAL) {
      float tw = t[w];
      float dw = (dv > 0) ? 1.f : 0.f;
      float4 a0 = reinterpret_cast<const float4*>(c1)[fl * 2];
      float4 a1 = reinterpret_cast<const float4*>(c1)[fl * 2 + 1];
      float4 d0 = reinterpret_cast<const float4*>(c2)[fl * 2];
      float4 d1 = reinterpret_cast<const float4*>(c2)[fl * 2 + 1];
      float4 b0 = reinterpret_cast<const float4*>(bc)[fl * 2];
      float4 b1v = reinterpret_cast<const float4*>(bc)[fl * 2 + 1];
      o8[0] += tw * a0.x + dw * d0.x + b0.x;
      o8[1] += tw * a0.y + dw * d0.y + b0.y;
      o8[2] += tw * a0.z + dw * d0.z + b0.z;
      o8[3] += tw * a0.w + dw * d0.w + b0.w;
      o8[4] += tw * a1.x + dw * d1.x + b1v.x;
      o8[5] += tw * a1.y + dw * d1.y + b1v.y;
      o8[6] += tw * a1.z + dw * d1.z + b1v.z;
      o8[7] += tw * a1.w + dw * d1.w + b1v.w;
      float4* of = reinterpret_cast<float4*>(outp);
      of[w * 16 + fl * 2]     = make_float4(o8[0], o8[1], o8[2], o8[3]);
      of[w * 16 + fl * 2 + 1] = make_float4(o8[4], o8[5], o8[6], o8[7]);
    } else {
      __half2 p0 = __floats2half2_rn(o8[0], o8[1]);
      __half2 p1 = __floats2half2_rn(o8[2], o8[3]);
      __half2 p2 = __floats2half2_rn(o8[4], o8[5]);
      __half2 p3 = __floats2half2_rn(o8[6], o8[7]);
      uint4 pk;
      pk.x = *reinterpret_cast<unsigned*>(&p0);
      pk.y = *reinterpret_cast<unsigned*>(&p1);
      pk.z = *reinterpret_cast<unsigned*>(&p2);
      pk.w = *reinterpret_cast<unsigned*>(&p3);
      reinterpret_cast<uint4*>(outp)[w * 8 + fl] = pk;
    }
  }
}

// ---------------- launch ----------------
extern "C" void kernel_launch(void* const* d_in, const int* in_sizes, int n_in,
                              void* d_out, int out_size, void* d_ws, size_t ws_size,
                              hipStream_t stream) {
  const float* x      = (const float*)d_in[0];
  const int*   src    = (const int*)d_in[1];
  const int*   dst    = (const int*)d_in[2];
  const float* W_gat  = (const float*)d_in[3];
  const float* attn_l = (const float*)d_in[4];
  const float* attn_r = (const float*)d_in[5];
  const float* W1     = (const float*)d_in[6];
  const float* b1     = (const float*)d_in[7];
  const float* W2     = (const float*)d_in[8];
  const float* b2     = (const float*)d_in[9];
  const float* Wc     = (const float*)d_in[10];
  const float* bc     = (const float*)d_in[11];
  float* out = (float*)d_out;

  char* ws = (char*)d_ws;
  size_t off = 0;
  auto walloc = [&](size_t bytes) -> void* {
    void* p = ws + off;
    off += (bytes + 255) & ~size_t(255);
    return p;
  };
  __half* P16     = (__half*)walloc((size_t)N_NODES * 128 * 2);  // h16 / z / z3
  __half* F16     = (__half*)walloc((size_t)N_NODES * 128 * 2);  // csr -> h1 / z2
  int*    csr     = (int*)F16;   // overlay: per-node 256B regions map 1:1
  float*  er      = (float*)walloc((size_t)N_NODES * 4);
  float2* el2     = (float2*)walloc((size_t)N_NODES * 8);
  float*  tbuf    = (float*)walloc((size_t)N_NODES * 4);
  int*    deg     = (int*)walloc((size_t)N_NODES * 4);
  int2*   meta    = (int2*)walloc((size_t)N_NODES * CAP * 8);    // 25.6 MB
  int2*   ovf     = (int2*)walloc((size_t)OVF_CAP * 8);
  int2*   movf    = (int2*)walloc((size_t)OVF_CAP * 8);
  int*    ovfn    = (int*)walloc(256);
  __half* Wg_hl   = (__half*)walloc((size_t)32768 * 2);
  __half* WP_hl   = (__half*)walloc((size_t)16384 * 2);
  float*  W12     = (float*)walloc((size_t)16384 * 4);
  float*  c12     = (float*)walloc((size_t)128 * 4);
  float*  c1      = (float*)walloc((size_t)64 * 4);
  float*  c2      = (float*)walloc((size_t)64 * 4);

  const dim3 blk(256);
  const int nwave_blocks = (N_NODES + 3) / 4;

  // K0: prep_a + zero-fill (deg, el2, ovfn)
  k0_prep_zero<<<dim3(NPREPA_BLK + NZERO_BLK), blk, 0, stream>>>(
      W_gat, W1, W2, b1, Wg_hl, W12, c12, deg, reinterpret_cast<float*>(el2), ovfn);
  // K1: csr-build FIRST (4 edges/thr), then prepP, then mgemm128 trailing
  k1_fused<<<dim3(NEDGE4_BLK + NPREPP_BLK + NGEMM_BLK), blk, 0, stream>>>(
      src, dst, deg, csr, reinterpret_cast<float*>(el2), ovf, ovfn,
      W12, c12, Wc, b2, WP_hl, c1, c2,
      x, Wg_hl, P16, attn_l, attn_r, el2, er, N_NODES);

  // fused: edge softmax (fixed meta + t) + h1 = elu(A h16)  [F16, overlays csr]
  aggsm_k<<<dim3(nwave_blocks), blk, 0, stream>>>(
      deg, csr, el2, er, meta, movf, ovf, ovfn, tbuf, P16, F16, N_NODES);
  // z = fp16(h1 @ Wp)  [P16, 64-dim]
  mgemm64_k<<<dim3(NGEMM_BLK), blk, 0, stream>>>(F16, WP_hl, P16, N_NODES);
  // z2 = A z  [F16], z3 = A z2  [P16], logits = A z3 + t*c1 + d*c2 + bc
  agg64v_k<false><<<dim3(nwave_blocks), blk, 0, stream>>>(deg, meta, movf, ovf, ovfn, P16, nullptr, nullptr, nullptr, nullptr, F16, N_NODES);
  agg64v_k<false><<<dim3(nwave_blocks), blk, 0, stream>>>(deg, meta, movf, ovf, ovfn, F16, nullptr, nullptr, nullptr, nullptr, P16, N_NODES);
  agg64v_k<true><<<dim3(nwave_blocks), blk, 0, stream>>>(deg, meta, movf, ovf, ovfn, P16, tbuf, c1, c2, bc, out, N_NODES);
}

// Round 10
// 244.276 us; speedup vs baseline: 1.0672x; 1.0672x over previous
//
#include <hip/hip_runtime.h>
#include <hip/hip_fp16.h>
#include <math.h>

#define N_NODES 50000
#define N_EDGES 800000
#define CAP 64                     // fixed per-node csr/meta capacity (deg>CAP -> ovf list)
#define OVF_CAP 65536
// dims: IN=128, HIDDEN=128, NUM_CLASSES=64 (hard-coded)
// Algebra: GraphConv chain is linear ->
//   logits = A^3 (h1 @ Wp) + t*c1 + d*c2 + bc
//   Wp = W1@W2@Wc, c1 = b1@W2@Wc, c2 = b2@Wc, d[v] = [deg_v>0] (=sum alpha), t = A d.
// Round-10 = round-8 base (best 249.9) + ONE delta: 4 edges/thread in the csr build
//   (4 independent load->atomic->store chains in flight), KEEPING round-8's
//   GEMM-first block order. Round-9 regression (k1 62->77) attributed to the
//   trailing-GEMM tail, not batching -- batching itself was never isolated.
// Round-9 lesson: GEMM blocks must LEAD (coarse blocks trailing = bad tail).
// Round-8 lesson: k1 occupancy is phase-averaged; LDS wasn't the cap.
// Round-7 lesson: single-pass fixed-cap CSR works.
// Round-6 lesson: latency-bound edge passes absorb compute blocks for free.
// Round-3 lesson: keep simple dual-chain gather loops; pads gather node0 (L1-hot).

typedef _Float16 half8 __attribute__((ext_vector_type(8)));
typedef float floatx16 __attribute__((ext_vector_type(16)));

#define NPREPA_BLK 129   // 129*256 = 33024 >= 32896
#define NZERO_BLK 587    // 587*256 = 150272 >= 150001 (deg + el2 + ovfn)
#define NPREPP_BLK 33    // 33*256 = 8448 >= 8320
#define NGEMM_BLK 391    // ceil(50000/128)
#define NEDGE4_BLK 782   // 782*256*4 = 800768 >= 800000 (4 edges/thread)

// ---------------- K0: prep_a (blocks 0..128) + zero-fill (blocks 129..) ----------------
__global__ __launch_bounds__(256) void k0_prep_zero(const float* __restrict__ Wg,
                                                    const float* __restrict__ W1,
                                                    const float* __restrict__ W2,
                                                    const float* __restrict__ b1,
                                                    __half* __restrict__ Wg_hl,
                                                    float* __restrict__ W12,
                                                    float* __restrict__ c12,
                                                    int* __restrict__ deg,
                                                    float* __restrict__ el2f,
                                                    int* __restrict__ ovfn) {
  int b = blockIdx.x;
  if (b >= NPREPA_BLK) {                 // ---- zero: deg, el2, ovfn ----
    int i = (b - NPREPA_BLK) * 256 + threadIdx.x;
    if (i < N_NODES) deg[i] = 0;
    else if (i < 3 * N_NODES) el2f[i - N_NODES] = 0.f;
    else if (i == 3 * N_NODES) *ovfn = 0;
    return;
  }
  // ---- prep_a: Wg -> hi/lo frags; W12 = W1@W2; c12 = b1@W2 ----
  int e = b * 256 + threadIdx.x;
  if (e < 16384) {
    _Float16* o = (_Float16*)Wg_hl;
    int k = e >> 7, n = e & 127;
    float w = Wg[k * 128 + n];
    _Float16 hi = (_Float16)w;
    float lo = w - (float)hi;
    int oi = (((k >> 3) * 128 + n) << 3) | (k & 7);
    o[oi] = hi;
    o[16384 + oi] = (_Float16)lo;
  } else if (e < 32768) {
    int local = e - 16384;
    int k = local >> 7, n = local & 127;
    float acc = 0.f;
    for (int j = 0; j < 128; ++j) acc = fmaf(W1[k * 128 + j], W2[j * 128 + n], acc);
    W12[k * 128 + n] = acc;
  } else if (e < 32896) {
    int n = e - 32768;
    float acc = 0.f;
    for (int j = 0; j < 128; ++j) acc = fmaf(b1[j], W2[j * 128 + n], acc);
    c12[n] = acc;
  }
}

// ---------------- MFMA GEMM body: C16[M x NCOL] = fp16( A[M x 128] @ (Whi+Wlo) ) ----------------
// Two-phase A-staging: 8 k-chunks at a time through a 16.6 KB LDS buffer; all 8
// frags end in VGPRs before the MFMA loop. ELR epilogue writes el2.x and er.
template <int NCOL, bool A16, bool ELR>
__device__ __forceinline__ void mgemm_body(int bid, const void* __restrict__ Ap,
                                           const __half* __restrict__ Whl,
                                           __half* __restrict__ C16, int M,
                                           const float* __restrict__ al,
                                           const float* __restrict__ ar,
                                           float* __restrict__ el2x,
                                           float* __restrict__ er) {
  __shared__ __half Al[8][129][8];       // 16.5 KB
  const int tid  = threadIdx.x;
  const int row0 = bid * 128;
  const int lane = tid & 63;
  const int lane31 = lane & 31;
  const int q = lane >> 5;
  const int r = tid >> 6;

  half8 afr[8];
  #pragma unroll
  for (int h = 0; h < 2; ++h) {
    if (h) __syncthreads();              // prior frag reads done before overwrite
    if (A16) {
      const uint4* A8 = (const uint4*)Ap;
      #pragma unroll
      for (int i = 0; i < 4; ++i) {
        int idx = tid + i * 256;
        int row = idx >> 3, c = idx & 7;   // 128 rows x 8 chunks
        int grow = row0 + row;
        uint4 v = make_uint4(0u, 0u, 0u, 0u);
        if (grow < M) v = A8[grow * 16 + h * 8 + c];
        *reinterpret_cast<uint4*>(&Al[c][row][0]) = v;
      }
    } else {
      const float4* A4 = (const float4*)Ap;
      #pragma unroll
      for (int i = 0; i < 4; ++i) {
        int idx = tid + i * 256;
        int row = idx >> 3, c = idx & 7;
        int grow = row0 + row;
        half8 hv = {};
        if (grow < M) {
          float4 a0 = A4[grow * 32 + (h * 8 + c) * 2];
          float4 a1 = A4[grow * 32 + (h * 8 + c) * 2 + 1];
          hv[0] = (_Float16)a0.x; hv[1] = (_Float16)a0.y;
          hv[2] = (_Float16)a0.z; hv[3] = (_Float16)a0.w;
          hv[4] = (_Float16)a1.x; hv[5] = (_Float16)a1.y;
          hv[6] = (_Float16)a1.z; hv[7] = (_Float16)a1.w;
        }
        *reinterpret_cast<half8*>(&Al[c][row][0]) = hv;
      }
    }
    __syncthreads();
    #pragma unroll
    for (int s2 = 0; s2 < 4; ++s2) {     // global chunk 2s+q, local chunk 2*s2+q
      afr[h * 4 + s2] =
          *reinterpret_cast<const half8*>(&Al[2 * s2 + q][r * 32 + lane31][0]);
    }
  }

  const half8* B8 = reinterpret_cast<const half8*>(Whl);
  const int KN8 = 16 * NCOL;

  float elp[16], erp[16];
  if (ELR) {
    #pragma unroll
    for (int i = 0; i < 16; ++i) { elp[i] = 0.f; erp[i] = 0.f; }
  }

  #pragma unroll
  for (int tc = 0; tc < NCOL / 32; ++tc) {
    floatx16 acc = {};
    int nbase = tc * 32 + lane31;
    #pragma unroll
    for (int s = 0; s < 8; ++s) {
      int ci = (2 * s + q) * NCOL + nbase;
      half8 bl = B8[KN8 + ci];
      half8 bh = B8[ci];
      acc = __builtin_amdgcn_mfma_f32_32x32x16_f16(afr[s], bl, acc, 0, 0, 0);
      acc = __builtin_amdgcn_mfma_f32_32x32x16_f16(afr[s], bh, acc, 0, 0, 0);
    }
    if (ELR) {
      float alv = al[nbase], arv = ar[nbase];
      #pragma unroll
      for (int i = 0; i < 16; ++i) {
        elp[i] = fmaf(acc[i], alv, elp[i]);
        erp[i] = fmaf(acc[i], arv, erp[i]);
      }
    }
    #pragma unroll
    for (int i = 0; i < 16; ++i) {
      int rl = (i & 3) + 8 * (i >> 2) + 4 * q;
      int grow = row0 + r * 32 + rl;
      if (grow < M) C16[grow * NCOL + nbase] = __float2half(acc[i]);
    }
  }

  if (ELR) {
    #pragma unroll
    for (int off = 1; off <= 16; off <<= 1) {
      #pragma unroll
      for (int i = 0; i < 16; ++i) {
        elp[i] += __shfl_xor(elp[i], off);
        erp[i] += __shfl_xor(erp[i], off);
      }
    }
    if (lane31 == 0) {
      #pragma unroll
      for (int i = 0; i < 16; ++i) {
        int rl = (i & 3) + 8 * (i >> 2) + 4 * q;
        int grow = row0 + r * 32 + rl;
        if (grow < M) {
          er[grow] = erp[i];
          el2x[2 * grow] = elp[i];     // .x only; .y written by CSR-build path
        }
      }
    }
  }
}

// ---------------- K1: prepP (0..32) + mgemm128 (33..423) + csr-build (424.., 4 e/thr) ----------------
// GEMM-first order (round-9 lesson); build blocks trail with fine granularity.
// Single-pass CSR: 4 independent load->atomicAdd->store chains per thread.
__global__ __launch_bounds__(256) void k1_fused(const int* __restrict__ src,
                                                const int* __restrict__ dst,
                                                int* __restrict__ deg,
                                                int* __restrict__ csr,
                                                float* __restrict__ el2f,
                                                int2* __restrict__ ovf,
                                                int* __restrict__ ovfn,
                                                const float* __restrict__ W12,
                                                const float* __restrict__ c12,
                                                const float* __restrict__ Wc,
                                                const float* __restrict__ b2,
                                                __half* __restrict__ WPhl,
                                                float* __restrict__ c1,
                                                float* __restrict__ c2,
                                                const float* __restrict__ x,
                                                const __half* __restrict__ Wg_hl,
                                                __half* __restrict__ P16,
                                                const float* __restrict__ al,
                                                const float* __restrict__ ar,
                                                float2* __restrict__ el2,
                                                float* __restrict__ er, int N) {
  int b = blockIdx.x;
  if (b >= NPREPP_BLK + NGEMM_BLK) {     // ---- csr build: 4 edges per thread ----
    int eb = (b - NPREPP_BLK - NGEMM_BLK) * 1024 + threadIdx.x;  // + {0,256,512,768}
    int d[4], s[4], rr[4];
    bool v[4];
    #pragma unroll
    for (int u = 0; u < 4; ++u) {        // 4 independent loads in flight
      int e = eb + u * 256;
      v[u] = (e < N_EDGES);
      d[u] = v[u] ? dst[e] : 0;
      s[u] = v[u] ? src[e] : 0;
    }
    #pragma unroll
    for (int u = 0; u < 4; ++u)          // 4 independent atomics in flight
      rr[u] = v[u] ? atomicAdd(&deg[d[u]], 1) : 0;
    #pragma unroll
    for (int u = 0; u < 4; ++u) {
      if (!v[u]) continue;
      if (rr[u] == 0) el2f[2 * d[u] + 1] = 1.0f;
      if (rr[u] < CAP) {
        csr[d[u] * CAP + rr[u]] = s[u];
      } else {
        int j = atomicAdd(ovfn, 1);
        if (j < OVF_CAP) ovf[j] = make_int2(d[u], s[u]);
      }
    }
    return;
  }
  if (b >= NPREPP_BLK) {                 // ---- mgemm128: h16, el2.x, er ----
    mgemm_body<128, false, true>(b - NPREPP_BLK, x, Wg_hl, P16, N, al, ar,
                                 reinterpret_cast<float*>(el2), er);
    return;
  }
  // ---- prepP: Wp = W12@Wc -> hi/lo frags; c1 = c12@Wc; c2 = b2@Wc ----
  int e = b * 256 + threadIdx.x;
  _Float16* o = (_Float16*)WPhl;
  if (e < 8192) {
    int k = e >> 6, n = e & 63;
    float acc = 0.f;
    for (int j = 0; j < 128; ++j) acc = fmaf(W12[k * 128 + j], Wc[j * 64 + n], acc);
    _Float16 hi = (_Float16)acc;
    float lo = acc - (float)hi;
    int oi = (((k >> 3) * 64 + n) << 3) | (k & 7);
    o[oi] = hi;
    o[8192 + oi] = (_Float16)lo;
  } else if (e < 8256) {
    int n = e - 8192;
    float acc = 0.f;
    for (int j = 0; j < 128; ++j) acc = fmaf(c12[j], Wc[j * 64 + n], acc);
    c1[n] = acc;
  } else if (e < 8320) {
    int n = e - 8256;
    float acc = 0.f;
    for (int j = 0; j < 128; ++j) acc = fmaf(b2[j], Wc[j * 64 + n], acc);
    c2[n] = acc;
  }
}

// ---------------- standalone mgemm64 wrapper ----------------
__global__ __launch_bounds__(256) void mgemm64_k(const void* __restrict__ Ap,
                                                 const __half* __restrict__ Whl,
                                                 __half* __restrict__ C16, int M) {
  mgemm_body<64, true, false>(blockIdx.x, Ap, Whl, C16, M, nullptr, nullptr, nullptr, nullptr);
}

__device__ inline void fma8(float2 acc[4], uint4 u, float a) {
  __half2* h = reinterpret_cast<__half2*>(&u);
  #pragma unroll
  for (int j = 0; j < 4; ++j) {
    float2 f = __half22float2(h[j]);
    acc[j].x = fmaf(a, f.x, acc[j].x);
    acc[j].y = fmaf(a, f.y, acc[j].y);
  }
}

// ---------------- fused edge-softmax + t + agg 128 (GAT layer), LDS-staged meta ----------------
// Fixed-capacity layout: node w's slots = [w*CAP, w*CAP+pcnt), pcnt=round16(deg) in [16,64].
// Softmax in-register -> meta {src*16, alpha} (pads {0,0}) AND per-wave LDS copy.
// NOTE: out (h1) overlays csr: each node's csr slots are read ONLY by its own wave,
// before that wave writes out[w] over the same 256B region. t[w] = sum alpha*[deg_src>0].
__global__ __launch_bounds__(256) void aggsm_k(const int* __restrict__ deg,
                                               const int* __restrict__ csr,
                                               const float2* __restrict__ el2,
                                               const float* __restrict__ er,
                                               int2* __restrict__ meta,
                                               int2* __restrict__ meta_ovf,
                                               const int2* __restrict__ ovf,
                                               const int* __restrict__ ovfn,
                                               float* __restrict__ t,
                                               const __half* __restrict__ hp,
                                               __half* __restrict__ out, int N) {
  __shared__ int2 lmeta[4][64];
  int wv   = threadIdx.x >> 6;
  int w    = (blockIdx.x * 256 + threadIdx.x) >> 6;
  int lane = threadIdx.x & 63;
  if (w >= N) return;
  int o0  = w * CAP;
  int cnt = deg[w];
  int q  = lane >> 4;
  int fl = lane & 15;
  const uint4* hpq = reinterpret_cast<const uint4*>(hp);

  int pcnt;
  if (cnt <= CAP) {                      // wave-uniform fast path (covers cnt==0)
    pcnt = (cnt + 15) & ~15;
    if (pcnt < 16) pcnt = 16;
    bool valid = lane < cnt;
    float erv = er[w];
    int s = 0;
    float ev = -3.4e38f, flag = 0.f;
    if (valid) {
      s = csr[o0 + lane];
      float2 e2 = el2[s];
      float e0 = e2.x + erv;
      ev = (e0 >= 0.f) ? e0 : 0.2f * e0;
      flag = e2.y;
    }
    float m = ev;
    #pragma unroll
    for (int off = 32; off; off >>= 1) m = fmaxf(m, __shfl_xor(m, off));
    float ee = valid ? __expf(ev - m) : 0.f;
    float sum = ee, tp = ee * flag;
    #pragma unroll
    for (int off = 32; off; off >>= 1) {
      sum += __shfl_xor(sum, off);
      tp  += __shfl_xor(tp, off);
    }
    float inv = (cnt > 0) ? 1.f / sum : 0.f;
    int2 mm = make_int2(0, 0);
    if (valid) mm = make_int2(s * 16, __float_as_int(ee * inv));
    if (lane < pcnt) meta[o0 + lane] = mm;
    lmeta[wv][lane] = mm;
    if (lane == 0) t[w] = tp * inv;
  } else {                               // rare generic path (degree > CAP): 64 fixed + ovf
    pcnt = CAP;
    int ovn = *ovfn;
    if (ovn > OVF_CAP) ovn = OVF_CAP;
    float erv = er[w];
    int s0 = csr[o0 + lane];             // all 64 slots valid
    float2 e20 = el2[s0];
    float ev0 = e20.x + erv;
    ev0 = (ev0 >= 0.f) ? ev0 : 0.2f * ev0;
    float m = ev0;
    for (int j = lane; j < ovn; j += 64) {
      int2 ov = ovf[j];
      if (ov.x == w) {
        float2 e2 = el2[ov.y];
        float ev = e2.x + erv;
        ev = (ev >= 0.f) ? ev : 0.2f * ev;
        m = fmaxf(m, ev);
      }
    }
    #pragma unroll
    for (int off = 32; off; off >>= 1) m = fmaxf(m, __shfl_xor(m, off));
    float ee0 = __expf(ev0 - m);
    float sum = ee0, tacc = ee0 * e20.y;
    for (int j = lane; j < ovn; j += 64) {
      int2 ov = ovf[j];
      if (ov.x == w) {
        float2 e2 = el2[ov.y];
        float ev = e2.x + erv;
        ev = (ev >= 0.f) ? ev : 0.2f * ev;
        float ee = __expf(ev - m);
        meta_ovf[j] = make_int2(ov.y * 16, __float_as_int(ee));
        sum += ee;
        tacc += ee * e2.y;
      }
    }
    #pragma unroll
    for (int off = 32; off; off >>= 1) {
      sum  += __shfl_xor(sum, off);
      tacc += __shfl_xor(tacc, off);
    }
    float inv = 1.f / sum;
    if (lane == 0) t[w] = tacc * inv;
    int2 mm = make_int2(s0 * 16, __float_as_int(ee0 * inv));
    meta[o0 + lane] = mm;
    lmeta[wv][lane] = mm;
    for (int j = lane; j < ovn; j += 64) {
      if (ovf[j].x == w) {
        int2 t2 = meta_ovf[j];
        meta_ovf[j] = make_int2(t2.x, __float_as_int(__int_as_float(t2.y) * inv));
      }
    }
  }

  // mask-free aggregation off LDS meta; ovf tail for deg>CAP nodes only.
  float2 acc0[4] = {}, acc1[4] = {};
  int pc = pcnt;                         // multiple of 16, in [16, 64]
  int2 mA = lmeta[wv][q], mB = lmeta[wv][4 + q];
  for (int base = 8; base < pc; base += 8) {
    int2 nA = lmeta[wv][base + q], nB = lmeta[wv][base + 4 + q];
    uint4 vA = hpq[mA.x + fl], vB = hpq[mB.x + fl];
    fma8(acc0, vA, __int_as_float(mA.y));
    fma8(acc1, vB, __int_as_float(mB.y));
    mA = nA; mB = nB;
  }
  {
    uint4 vA = hpq[mA.x + fl], vB = hpq[mB.x + fl];
    fma8(acc0, vA, __int_as_float(mA.y));
    fma8(acc1, vB, __int_as_float(mB.y));
  }
  if (cnt > CAP) {                       // overflow tail (expected empty)
    int ovn = *ovfn;
    if (ovn > OVF_CAP) ovn = OVF_CAP;
    for (int j = q; j < ovn; j += 4) {
      if (ovf[j].x == w) {
        int2 mm2 = meta_ovf[j];
        fma8(acc0, hpq[mm2.x + fl], __int_as_float(mm2.y));
      }
    }
  }
  #pragma unroll
  for (int j = 0; j < 4; ++j) { acc0[j].x += acc1[j].x; acc0[j].y += acc1[j].y; }
  #pragma unroll
  for (int off = 16; off <= 32; off <<= 1) {
    #pragma unroll
    for (int j = 0; j < 4; ++j) {
      acc0[j].x += __shfl_xor(acc0[j].x, off);
      acc0[j].y += __shfl_xor(acc0[j].y, off);
    }
  }
  if (q == 0) {
    float o8[8];
    #pragma unroll
    for (int j = 0; j < 4; ++j) { o8[2 * j] = acc0[j].x; o8[2 * j + 1] = acc0[j].y; }
    #pragma unroll
    for (int j = 0; j < 8; ++j) o8[j] = (o8[j] > 0.f) ? o8[j] : (__expf(o8[j]) - 1.f);
    __half2 p0 = __floats2half2_rn(o8[0], o8[1]);
    __half2 p1 = __floats2half2_rn(o8[2], o8[3]);
    __half2 p2 = __floats2half2_rn(o8[4], o8[5]);
    __half2 p3 = __floats2half2_rn(o8[6], o8[7]);
    uint4 pk;
    pk.x = *reinterpret_cast<unsigned*>(&p0);
    pk.y = *reinterpret_cast<unsigned*>(&p1);
    pk.z = *reinterpret_cast<unsigned*>(&p2);
    pk.w = *reinterpret_cast<unsigned*>(&p3);
    *reinterpret_cast<uint4*>(&out[w * 128 + fl * 8]) = pk;
  }
}

// ---------------- agg 64-feat via fixed-capacity meta, mask-free, 2-deep dual chain ----------------
// pcnt = round16(deg) in [16,64]; dual chains (slots o+16k / o+8+16k) for MLP.
// deg>CAP nodes add the ovf tail. FINAL adds t*c1 + d*c2 + bc and writes f32; else fp16.
template <bool FINAL>
__global__ __launch_bounds__(256) void agg64v_k(const int* __restrict__ deg,
                                                const int2* __restrict__ meta,
                                                const int2* __restrict__ meta_ovf,
                                                const int2* __restrict__ ovf,
                                                const int* __restrict__ ovfn,
                                                const __half* __restrict__ zp,
                                                const float* __restrict__ t,
                                                const float* __restrict__ c1,
                                                const float* __restrict__ c2,
                                                const float* __restrict__ bc,
                                                void* __restrict__ outp, int N) {
  int w    = (blockIdx.x * 256 + threadIdx.x) >> 6;
  int lane = threadIdx.x & 63;
  if (w >= N) return;
  int dv = deg[w];
  int pc = (dv + 15) & ~15;
  if (pc < 16) pc = 16;
  if (pc > CAP) pc = CAP;
  int o0 = w * CAP, o1 = w * CAP + pc;
  int o   = lane >> 3;
  int fl  = lane & 7;
  const uint4* hpq = reinterpret_cast<const uint4*>(zp);

  float2 acc0[4] = {}, acc1[4] = {};
  int p = o0 + o;
  int2 mA = meta[p], mB = meta[p + 8];
  for (; p + 16 < o1; p += 16) {
    int2 nA = meta[p + 16], nB = meta[p + 24];
    uint4 vA = hpq[(mA.x >> 1) + fl];
    uint4 vB = hpq[(mB.x >> 1) + fl];
    fma8(acc0, vA, __int_as_float(mA.y));
    fma8(acc1, vB, __int_as_float(mB.y));
    mA = nA; mB = nB;
  }
  {
    uint4 vA = hpq[(mA.x >> 1) + fl];
    uint4 vB = hpq[(mB.x >> 1) + fl];
    fma8(acc0, vA, __int_as_float(mA.y));
    fma8(acc1, vB, __int_as_float(mB.y));
  }
  if (dv > CAP) {                        // overflow tail (expected empty)
    int ovn = *ovfn;
    if (ovn > OVF_CAP) ovn = OVF_CAP;
    for (int j = o; j < ovn; j += 8) {
      if (ovf[j].x == w) {
        int2 mm2 = meta_ovf[j];
        fma8(acc0, hpq[(mm2.x >> 1) + fl], __int_as_float(mm2.y));
      }
    }
  }
  #pragma unroll
  for (int j = 0; j < 4; ++j) { acc0[j].x += acc1[j].x; acc0[j].y += acc1[j].y; }
  #pragma unroll
  for (int off = 8; off <= 32; off <<= 1) {
    #pragma unroll
    for (int j = 0; j < 4; ++j) {
      acc0[j].x += __shfl_xor(acc0[j].x, off);
      acc0[j].y += __shfl_xor(acc0[j].y, off);
    }
  }
  if (o == 0) {
    float o8[8];
    #pragma unroll
    for (int j = 0; j < 4; ++j) { o8[2 * j] = acc0[j].x; o8[2 * j + 1] = acc0[j].y; }
    if (FINAL) {
      float tw = t[w];
      float dw = (dv > 0) ? 1.f : 0.f;
      float4 a0 = reinterpret_cast<const float4*>(c1)[fl * 2];
      float4 a1 = reinterpret_cast<const float4*>(c1)[fl * 2 + 1];
      float4 d0 = reinterpret_cast<const float4*>(c2)[fl * 2];
      float4 d1 = reinterpret_cast<const float4*>(c2)[fl * 2 + 1];
      float4 b0 = reinterpret_cast<const float4*>(bc)[fl * 2];
      float4 b1v = reinterpret_cast<const float4*>(bc)[fl * 2 + 1];
      o8[0] += tw * a0.x + dw * d0.x + b0.x;
      o8[1] += tw * a0.y + dw * d0.y + b0.y;
      o8[2] += tw * a0.z + dw * d0.z + b0.z;
      o8[3] += tw * a0.w + dw * d0.w + b0.w;
      o8[4] += tw * a1.x + dw * d1.x + b1v.x;
      o8[5] += tw * a1.y + dw * d1.y + b1v.y;
      o8[6] += tw * a1.z + dw * d1.z + b1v.z;
      o8[7] += tw * a1.w + dw * d1.w + b1v.w;
      float4* of = reinterpret_cast<float4*>(outp);
      of[w * 16 + fl * 2]     = make_float4(o8[0], o8[1], o8[2], o8[3]);
      of[w * 16 + fl * 2 + 1] = make_float4(o8[4], o8[5], o8[6], o8[7]);
    } else {
      __half2 p0 = __floats2half2_rn(o8[0], o8[1]);
      __half2 p1 = __floats2half2_rn(o8[2], o8[3]);
      __half2 p2 = __floats2half2_rn(o8[4], o8[5]);
      __half2 p3 = __floats2half2_rn(o8[6], o8[7]);
      uint4 pk;
      pk.x = *reinterpret_cast<unsigned*>(&p0);
      pk.y = *reinterpret_cast<unsigned*>(&p1);
      pk.z = *reinterpret_cast<unsigned*>(&p2);
      pk.w = *reinterpret_cast<unsigned*>(&p3);
      reinterpret_cast<uint4*>(outp)[w * 8 + fl] = pk;
    }
  }
}

// ---------------- launch ----------------
extern "C" void kernel_launch(void* const* d_in, const int* in_sizes, int n_in,
                              void* d_out, int out_size, void* d_ws, size_t ws_size,
                              hipStream_t stream) {
  const float* x      = (const float*)d_in[0];
  const int*   src    = (const int*)d_in[1];
  const int*   dst    = (const int*)d_in[2];
  const float* W_gat  = (const float*)d_in[3];
  const float* attn_l = (const float*)d_in[4];
  const float* attn_r = (const float*)d_in[5];
  const float* W1     = (const float*)d_in[6];
  const float* b1     = (const float*)d_in[7];
  const float* W2     = (const float*)d_in[8];
  const float* b2     = (const float*)d_in[9];
  const float* Wc     = (const float*)d_in[10];
  const float* bc     = (const float*)d_in[11];
  float* out = (float*)d_out;

  char* ws = (char*)d_ws;
  size_t off = 0;
  auto walloc = [&](size_t bytes) -> void* {
    void* p = ws + off;
    off += (bytes + 255) & ~size_t(255);
    return p;
  };
  __half* P16     = (__half*)walloc((size_t)N_NODES * 128 * 2);  // h16 / z / z3
  __half* F16     = (__half*)walloc((size_t)N_NODES * 128 * 2);  // csr -> h1 / z2
  int*    csr     = (int*)F16;   // overlay: per-node 256B regions map 1:1
  float*  er      = (float*)walloc((size_t)N_NODES * 4);
  float2* el2     = (float2*)walloc((size_t)N_NODES * 8);
  float*  tbuf    = (float*)walloc((size_t)N_NODES * 4);
  int*    deg     = (int*)walloc((size_t)N_NODES * 4);
  int2*   meta    = (int2*)walloc((size_t)N_NODES * CAP * 8);    // 25.6 MB
  int2*   ovf     = (int2*)walloc((size_t)OVF_CAP * 8);
  int2*   movf    = (int2*)walloc((size_t)OVF_CAP * 8);
  int*    ovfn    = (int*)walloc(256);
  __half* Wg_hl   = (__half*)walloc((size_t)32768 * 2);
  __half* WP_hl   = (__half*)walloc((size_t)16384 * 2);
  float*  W12     = (float*)walloc((size_t)16384 * 4);
  float*  c12     = (float*)walloc((size_t)128 * 4);
  float*  c1      = (float*)walloc((size_t)64 * 4);
  float*  c2      = (float*)walloc((size_t)64 * 4);

  const dim3 blk(256);
  const int nwave_blocks = (N_NODES + 3) / 4;

  // K0: prep_a + zero-fill (deg, el2, ovfn)
  k0_prep_zero<<<dim3(NPREPA_BLK + NZERO_BLK), blk, 0, stream>>>(
      W_gat, W1, W2, b1, Wg_hl, W12, c12, deg, reinterpret_cast<float*>(el2), ovfn);
  // K1: prepP + mgemm128 first, then csr-build (4 edges/thr) trailing
  k1_fused<<<dim3(NPREPP_BLK + NGEMM_BLK + NEDGE4_BLK), blk, 0, stream>>>(
      src, dst, deg, csr, reinterpret_cast<float*>(el2), ovf, ovfn,
      W12, c12, Wc, b2, WP_hl, c1, c2,
      x, Wg_hl, P16, attn_l, attn_r, el2, er, N_NODES);

  // fused: edge softmax (fixed meta + t) + h1 = elu(A h16)  [F16, overlays csr]
  aggsm_k<<<dim3(nwave_blocks), blk, 0, stream>>>(
      deg, csr, el2, er, meta, movf, ovf, ovfn, tbuf, P16, F16, N_NODES);
  // z = fp16(h1 @ Wp)  [P16, 64-dim]
  mgemm64_k<<<dim3(NGEMM_BLK), blk, 0, stream>>>(F16, WP_hl, P16, N_NODES);
  // z2 = A z  [F16], z3 = A z2  [P16], logits = A z3 + t*c1 + d*c2 + bc
  agg64v_k<false><<<dim3(nwave_blocks), blk, 0, stream>>>(deg, meta, movf, ovf, ovfn, P16, nullptr, nullptr, nullptr, nullptr, F16, N_NODES);
  agg64v_k<false><<<dim3(nwave_blocks), blk, 0, stream>>>(deg, meta, movf, ovf, ovfn, F16, nullptr, nullptr, nullptr, nullptr, P16, N_NODES);
  agg64v_k<true><<<dim3(nwave_blocks), blk, 0, stream>>>(deg, meta, movf, ovf, ovfn, P16, tbuf, c1, c2, bc, out, N_NODES);
}